// Round 2
// baseline (850.858 us; speedup 1.0000x reference)
//
#include <hip/hip_runtime.h>
#include <hip/hip_bf16.h>
#include <stdint.h>

constexpr int BB = 4;
constexpr int SS = 2048;
constexpr int DD = 768;
constexpr int HH = 12;
constexpr int DKK = 64;
constexpr int DFF2 = 3072;
constexpr int MR = BB * SS;   // 8192 rows

typedef __attribute__((ext_vector_type(4))) short short4v;
typedef __attribute__((ext_vector_type(8))) short short8v;
typedef __attribute__((ext_vector_type(4))) float f32x4;
typedef __attribute__((ext_vector_type(4))) float float4v;

static __device__ inline short f2bs(float f) {
    __hip_bfloat16 h = __float2bfloat16(f);
    return (short)__builtin_bit_cast(unsigned short, h);
}
static __device__ inline float bs2f(short s) {
    __hip_bfloat16 h = __builtin_bit_cast(__hip_bfloat16, (unsigned short)s);
    return __bfloat162float(h);
}

static __device__ inline void glds16(const void* g, void* l) {
    __builtin_amdgcn_global_load_lds(
        (const __attribute__((address_space(1))) void*)g,
        (__attribute__((address_space(3))) void*)l, 16, 0, 0);
}

// ---------------- cast fp32 -> bf16 ----------------
__global__ __launch_bounds__(256) void cast_f32_bf16(const float* __restrict__ in,
                                                     short* __restrict__ out, int n) {
    int i = (blockIdx.x * 256 + threadIdx.x) * 4;
    if (i < n) {
        float4v v = *(const float4v*)&in[i];
        short4v o;
        o[0] = f2bs(v[0]); o[1] = f2bs(v[1]); o[2] = f2bs(v[2]); o[3] = f2bs(v[3]);
        *(short4v*)&out[i] = o;
    }
}

// ---------------- transpose + cast: Wt[n][k] = W[k][n] ----------------
__global__ __launch_bounds__(256) void transpose_cast(const float* __restrict__ W,
                                                      short* __restrict__ Wt, int K, int N) {
    __shared__ float tile[32][33];
    int n0 = blockIdx.x * 32, k0 = blockIdx.y * 32;
    int tx = threadIdx.x & 31, ty = threadIdx.x >> 5;
    #pragma unroll
    for (int i = 0; i < 32; i += 8)
        tile[ty + i][tx] = W[(size_t)(k0 + ty + i) * N + n0 + tx];
    __syncthreads();
    #pragma unroll
    for (int i = 0; i < 32; i += 8)
        Wt[(size_t)(n0 + ty + i) * K + k0 + tx] = f2bs(tile[tx][ty + i]);
}

// ---------------- GEMM: C[M][N] = A[M][K] @ Bt[N][K]^T, bf16 MFMA (m97 structure) ----
// EPI: 0 = +bias, store bf16 row-major
//      1 = +bias, relu, store bf16 row-major
//      2 = QKV scatter: +bias{q,k,v}, q*=0.125, Q/K -> [B,H,S,64], V -> [B,H,64,S]^T
template <int EPI>
__global__ __launch_bounds__(256) void gemm_bt(
    const short* __restrict__ A, const short* __restrict__ Bt,
    int Nn, int Kn,
    const float* __restrict__ bias0, const float* __restrict__ bias1,
    const float* __restrict__ bias2,
    short* __restrict__ out0, short* __restrict__ out1, short* __restrict__ out2) {
    __shared__ short sA[128 * 32];
    __shared__ short sB[128 * 32];
    const int tid = threadIdx.x;
    const int wave = tid >> 6, lane = tid & 63;
    const int g = lane >> 4, qq = lane & 15;
    const int wm = (wave >> 1) * 64, wn = (wave & 1) * 64;
    const int m0 = blockIdx.y * 128, n0 = blockIdx.x * 128;

    // staging geometry: tile = 128x32 shorts = 8192B = 8 chunks of 1024B.
    // wave w writes chunks w and w+4; lane deposits 16B at base+lane*16.
    const int e0 = wave * 512 + lane * 8;      // shorts
    const int r0 = e0 >> 5, c0 = e0 & 31;      // r1 = r0+64, c1 = c0
    short* lA0 = &sA[wave * 512]; short* lA1 = &sA[wave * 512 + 2048];
    short* lB0 = &sB[wave * 512]; short* lB1 = &sB[wave * 512 + 2048];

    const f32x4 zero = {0.0f, 0.0f, 0.0f, 0.0f};
    f32x4 acc[4][4];
    #pragma unroll
    for (int i = 0; i < 4; i++)
        #pragma unroll
        for (int j = 0; j < 4; j++) acc[i][j] = zero;

    for (int k0 = 0; k0 < Kn; k0 += 32) {
        __syncthreads();
        glds16(&A[(size_t)(m0 + r0) * Kn + k0 + c0], lA0);
        glds16(&A[(size_t)(m0 + r0 + 64) * Kn + k0 + c0], lA1);
        glds16(&Bt[(size_t)(n0 + r0) * Kn + k0 + c0], lB0);
        glds16(&Bt[(size_t)(n0 + r0 + 64) * Kn + k0 + c0], lB1);
        __syncthreads();
        short8v af[4], bf[4];
        #pragma unroll
        for (int i = 0; i < 4; i++) {
            short4v lo = *(const short4v*)&sA[(wm + i * 16 + qq) * 32 + 4 * g];
            short4v hi = *(const short4v*)&sA[(wm + i * 16 + qq) * 32 + 16 + 4 * g];
            af[i] = __builtin_shufflevector(lo, hi, 0, 1, 2, 3, 4, 5, 6, 7);
            short4v blo = *(const short4v*)&sB[(wn + i * 16 + qq) * 32 + 4 * g];
            short4v bhi = *(const short4v*)&sB[(wn + i * 16 + qq) * 32 + 16 + 4 * g];
            bf[i] = __builtin_shufflevector(blo, bhi, 0, 1, 2, 3, 4, 5, 6, 7);
        }
        #pragma unroll
        for (int i = 0; i < 4; i++)
            #pragma unroll
            for (int j = 0; j < 4; j++)
                acc[i][j] = __builtin_amdgcn_mfma_f32_16x16x32_bf16(af[i], bf[j], acc[i][j], 0, 0, 0);
    }

    if (EPI == 2) {
        int which = n0 / DD;
        const float* bias = (which == 0) ? bias0 : ((which == 1) ? bias1 : bias2);
        short* outp = (which == 0) ? out0 : ((which == 1) ? out1 : out2);
        float scale = (which == 0) ? 0.125f : 1.0f;
        #pragma unroll
        for (int i = 0; i < 4; i++)
            #pragma unroll
            for (int j = 0; j < 4; j++)
                #pragma unroll
                for (int r = 0; r < 4; r++) {
                    int row = m0 + wm + i * 16 + g * 4 + r;
                    int col = n0 - which * DD + wn + j * 16 + qq;
                    float vv = (acc[i][j][r] + bias[col]) * scale;
                    int b_ = row >> 11, s_ = row & 2047;
                    int h_ = col >> 6, d_ = col & 63;
                    if (which == 2)  // V transposed: [B,H,64,S]
                        outp[((size_t)(b_ * HH + h_) * DKK + d_) * SS + s_] = f2bs(vv);
                    else
                        outp[(((size_t)(b_ * HH + h_)) * SS + s_) * DKK + d_] = f2bs(vv);
                }
    } else {
        #pragma unroll
        for (int i = 0; i < 4; i++)
            #pragma unroll
            for (int j = 0; j < 4; j++)
                #pragma unroll
                for (int r = 0; r < 4; r++) {
                    int row = m0 + wm + i * 16 + g * 4 + r;
                    int col = n0 + wn + j * 16 + qq;
                    float vv = acc[i][j][r] + bias0[col];
                    if (EPI == 1) vv = fmaxf(vv, 0.0f);
                    out0[(size_t)row * Nn + col] = f2bs(vv);
                }
    }
}

// ---------------- flash attention, KVBLK=64, V^T input ----------------
// grid: (SS/64, BB*HH), block 256. Q pre-scaled by 1/sqrt(dk).
__global__ __launch_bounds__(256) void attn_kernel(
    const short* __restrict__ Q, const short* __restrict__ Kb,
    const short* __restrict__ Vt, const int* __restrict__ mask,
    short* __restrict__ ctx) {
    __shared__ short sK[64][72];   // [kv][d]
    __shared__ short sV[64][72];   // [d][kv]  (V^T tile)
    __shared__ short sP[4][16][72];
    const int tid = threadIdx.x;
    const int wave = tid >> 6, lane = tid & 63;
    const int g = lane >> 4, qq = lane & 15;
    const int bh = blockIdx.y;
    const int b_ = bh / HH;
    const int h_ = bh % HH;
    const int q0 = blockIdx.x * 64 + wave * 16;
    const size_t base = (size_t)bh * SS * DKK;
    const float L2E = 1.44269504088896f;

    // Q fragments (A operand), per-wave 16 rows
    short8v aq[2];
    #pragma unroll
    for (int c = 0; c < 2; c++) {
        const short* qp = &Q[base + (size_t)(q0 + qq) * DKK + c * 32 + 4 * g];
        short4v lo = *(const short4v*)qp;
        short4v hi = *(const short4v*)(qp + 16);
        aq[c] = __builtin_shufflevector(lo, hi, 0, 1, 2, 3, 4, 5, 6, 7);
    }

    const f32x4 zero = {0.0f, 0.0f, 0.0f, 0.0f};
    f32x4 cacc[4];
    #pragma unroll
    for (int i = 0; i < 4; i++) cacc[i] = zero;
    float mrow[4], lrow[4];
    #pragma unroll
    for (int r = 0; r < 4; r++) { mrow[r] = -INFINITY; lrow[r] = 0.0f; }

    // staging: 64x64 shorts per tile; thread does 2 x 16B loads per matrix
    const int sr = tid >> 3, scol = (tid & 7) * 8;  // iter adds 32 rows

    for (int kv0 = 0; kv0 < SS; kv0 += 64) {
        __syncthreads();
        #pragma unroll
        for (int it = 0; it < 2; it++) {
            int r = it * 32 + sr;
            *(short8v*)&sK[r][scol] =
                *(const short8v*)&Kb[base + (size_t)(kv0 + r) * DKK + scol];
            *(short8v*)&sV[r][scol] =
                *(const short8v*)&Vt[base + (size_t)r * SS + kv0 + scol];
        }
        __syncthreads();

        // scores = Q @ K^T  (four 16-col fragments)
        f32x4 sc[4];
        #pragma unroll
        for (int nf = 0; nf < 4; nf++) {
            f32x4 z = zero;
            #pragma unroll
            for (int c = 0; c < 2; c++) {
                short4v lo = *(const short4v*)&sK[nf * 16 + qq][c * 32 + 4 * g];
                short4v hi = *(const short4v*)&sK[nf * 16 + qq][c * 32 + 16 + 4 * g];
                short8v kf = __builtin_shufflevector(lo, hi, 0, 1, 2, 3, 4, 5, 6, 7);
                z = __builtin_amdgcn_mfma_f32_16x16x32_bf16(aq[c], kf, z, 0, 0, 0);
            }
            sc[nf] = z;
        }
        // mask (column-wise)
        #pragma unroll
        for (int nf = 0; nf < 4; nf++) {
            int mv = mask[b_ * SS + kv0 + nf * 16 + qq];
            if (mv == 0) {
                #pragma unroll
                for (int r = 0; r < 4; r++) sc[nf][r] = -1e9f;
            }
        }

        // online softmax per row (row = 4*g + r within the wave's 16-row tile)
        #pragma unroll
        for (int r = 0; r < 4; r++) {
            float t = fmaxf(fmaxf(sc[0][r], sc[1][r]), fmaxf(sc[2][r], sc[3][r]));
            t = fmaxf(t, __shfl_xor(t, 1));
            t = fmaxf(t, __shfl_xor(t, 2));
            t = fmaxf(t, __shfl_xor(t, 4));
            t = fmaxf(t, __shfl_xor(t, 8));
            float mnew = fmaxf(mrow[r], t);
            float alpha = exp2f((mrow[r] - mnew) * L2E);
            mrow[r] = mnew;
            float rs = 0.0f;
            #pragma unroll
            for (int nf = 0; nf < 4; nf++) {
                float p = exp2f((sc[nf][r] - mnew) * L2E);
                sc[nf][r] = p;
                rs += p;
            }
            rs += __shfl_xor(rs, 1); rs += __shfl_xor(rs, 2);
            rs += __shfl_xor(rs, 4); rs += __shfl_xor(rs, 8);
            lrow[r] = lrow[r] * alpha + rs;
            #pragma unroll
            for (int nf = 0; nf < 4; nf++) cacc[nf][r] *= alpha;
        }

        // P -> wave-private LDS (no barrier needed), read back as A-fragments
        #pragma unroll
        for (int nf = 0; nf < 4; nf++)
            #pragma unroll
            for (int r = 0; r < 4; r++)
                sP[wave][g * 4 + r][nf * 16 + qq] = f2bs(sc[nf][r]);
        short8v pa[2];
        #pragma unroll
        for (int c = 0; c < 2; c++) {
            short4v plo = *(const short4v*)&sP[wave][qq][c * 32 + 4 * g];
            short4v phi = *(const short4v*)&sP[wave][qq][c * 32 + 16 + 4 * g];
            pa[c] = __builtin_shufflevector(plo, phi, 0, 1, 2, 3, 4, 5, 6, 7);
        }
        #pragma unroll
        for (int nf = 0; nf < 4; nf++) {
            #pragma unroll
            for (int c = 0; c < 2; c++) {
                short4v blo = *(const short4v*)&sV[nf * 16 + qq][c * 32 + 4 * g];
                short4v bhi = *(const short4v*)&sV[nf * 16 + qq][c * 32 + 16 + 4 * g];
                short8v vf = __builtin_shufflevector(blo, bhi, 0, 1, 2, 3, 4, 5, 6, 7);
                cacc[nf] = __builtin_amdgcn_mfma_f32_16x16x32_bf16(pa[c], vf, cacc[nf], 0, 0, 0);
            }
        }
    }

    // write ctx [B,S,D] with col = h*64 + dk
    #pragma unroll
    for (int nf = 0; nf < 4; nf++)
        #pragma unroll
        for (int r = 0; r < 4; r++) {
            int row = q0 + g * 4 + r;
            int col = h_ * DKK + nf * 16 + qq;
            float vv = cacc[nf][r] / lrow[r];
            ctx[(size_t)(b_ * SS + row) * DD + col] = f2bs(vv);
        }
}

// ---------------- layernorm: out = LN(in1_f32 + in2_bf16) ----------------
template <int WB, int WF>
__global__ __launch_bounds__(256) void ln_fused(
    const float* __restrict__ in1, const short* __restrict__ in2,
    const float* __restrict__ gw, const float* __restrict__ bw,
    short* __restrict__ outb, float* __restrict__ outf) {
    const int row = blockIdx.x;
    const int tid = threadIdx.x;
    float v[3];
    #pragma unroll
    for (int i = 0; i < 3; i++) {
        int c = tid + i * 256;
        v[i] = in1[(size_t)row * DD + c] + bs2f(in2[(size_t)row * DD + c]);
    }
    float s = v[0] + v[1] + v[2];
    float s2 = v[0] * v[0] + v[1] * v[1] + v[2] * v[2];
    #pragma unroll
    for (int off = 1; off < 64; off <<= 1) {
        s += __shfl_xor(s, off);
        s2 += __shfl_xor(s2, off);
    }
    __shared__ float red[8];
    int wv = tid >> 6;
    if ((tid & 63) == 0) { red[wv] = s; red[4 + wv] = s2; }
    __syncthreads();
    s = red[0] + red[1] + red[2] + red[3];
    s2 = red[4] + red[5] + red[6] + red[7];
    float mu = s / DD;
    float var = s2 / DD - mu * mu;
    float rs = rsqrtf(var + 1e-5f);
    #pragma unroll
    for (int i = 0; i < 3; i++) {
        int c = tid + i * 256;
        float y = (v[i] - mu) * rs * gw[c] + bw[c];
        if (WB) outb[(size_t)row * DD + c] = f2bs(y);
        if (WF) outf[(size_t)row * DD + c] = y;
    }
}

extern "C" void kernel_launch(void* const* d_in, const int* in_sizes, int n_in,
                              void* d_out, int out_size, void* d_ws, size_t ws_size,
                              hipStream_t stream) {
    (void)in_sizes; (void)n_in; (void)out_size; (void)ws_size;
    const float* src = (const float*)d_in[0];
    const int* mask = (const int*)d_in[1];
    const float* Wq = (const float*)d_in[2];
    const float* bq = (const float*)d_in[3];
    const float* Wk = (const float*)d_in[4];
    const float* bk = (const float*)d_in[5];
    const float* Wv = (const float*)d_in[6];
    const float* bv = (const float*)d_in[7];
    const float* Wo = (const float*)d_in[8];
    const float* bo = (const float*)d_in[9];
    const float* W1 = (const float*)d_in[10];
    const float* b1 = (const float*)d_in[11];
    const float* W2 = (const float*)d_in[12];
    const float* b2 = (const float*)d_in[13];
    const float* ln1_g = (const float*)d_in[14];
    const float* ln1_b = (const float*)d_in[15];
    const float* ln2_g = (const float*)d_in[16];
    const float* ln2_b = (const float*)d_in[17];

    char* ws = (char*)d_ws;
    const size_t SB = (size_t)MR * DD * 2;            // 12582912 bytes (one [8192,768] bf16)
    short* src_b  = (short*)(ws);                     // R0: src_bf16 / attn_out / ffn2_out
    short* Wqkv_t = (short*)(ws + SB);                // R1
    short* qb     = (short*)(ws + SB + 3538944);      // R2: q,k,v^T,ctx (h aliases all of R2)
    short* kb_    = qb + (size_t)MR * DD;
    short* vb_    = kb_ + (size_t)MR * DD;            // V^T [B,H,64,S]
    short* ctxb   = vb_ + (size_t)MR * DD;
    short* hb     = qb;                               // [8192,3072] bf16, aliases q/k/v/ctx
    short* Wo_t   = (short*)(ws + SB + 3538944 + 4 * SB);          // R3
    short* x_b    = (short*)(ws + SB + 3538944 + 4 * SB + 1179648);// R4
    short* W1_t   = (short*)((char*)x_b + SB);                     // R5
    short* W2_t   = (short*)((char*)W1_t + 4718592);               // R6
    float* x_f    = (float*)((char*)W2_t + 4718592);               // R7: fp32 x for residual
    short* attn_b = src_b;
    short* ffn_b  = src_b;

    // 1. casts / transposes
    cast_f32_bf16<<<(MR * DD) / 1024, 256, 0, stream>>>(src, src_b, MR * DD);
    transpose_cast<<<dim3(24, 24), 256, 0, stream>>>(Wq, Wqkv_t, DD, DD);
    transpose_cast<<<dim3(24, 24), 256, 0, stream>>>(Wk, Wqkv_t + DD * DD, DD, DD);
    transpose_cast<<<dim3(24, 24), 256, 0, stream>>>(Wv, Wqkv_t + 2 * DD * DD, DD, DD);
    transpose_cast<<<dim3(24, 24), 256, 0, stream>>>(Wo, Wo_t, DD, DD);
    transpose_cast<<<dim3(96, 24), 256, 0, stream>>>(W1, W1_t, DD, DFF2);
    transpose_cast<<<dim3(24, 96), 256, 0, stream>>>(W2, W2_t, DFF2, DD);

    // 2. QKV projection (fused, N=2304) with scatter epilogue (V transposed)
    gemm_bt<2><<<dim3(2304 / 128, MR / 128), 256, 0, stream>>>(
        src_b, Wqkv_t, 2304, DD, bq, bk, bv, qb, kb_, vb_);

    // 3. attention
    attn_kernel<<<dim3(SS / 64, BB * HH), 256, 0, stream>>>(qb, kb_, vb_, mask, ctxb);

    // 4. output projection
    gemm_bt<0><<<dim3(DD / 128, MR / 128), 256, 0, stream>>>(
        ctxb, Wo_t, DD, DD, bo, nullptr, nullptr, attn_b, nullptr, nullptr);

    // 5. LN1: x = LN(src + attn_out) -> bf16 + fp32 in one pass
    ln_fused<1, 1><<<MR, 256, 0, stream>>>(src, attn_b, ln1_g, ln1_b, x_b, x_f);

    // 6. FFN
    gemm_bt<1><<<dim3(DFF2 / 128, MR / 128), 256, 0, stream>>>(
        x_b, W1_t, DFF2, DD, b1, nullptr, nullptr, hb, nullptr, nullptr);
    gemm_bt<0><<<dim3(DD / 128, MR / 128), 256, 0, stream>>>(
        hb, W2_t, DD, DFF2, b2, nullptr, nullptr, ffn_b, nullptr, nullptr);

    // 7. LN2 -> fp32 output
    ln_fused<0, 1><<<MR, 256, 0, stream>>>(x_f, ffn_b, ln2_g, ln2_b, nullptr, (float*)d_out);
}

// Round 3
// 413.339 us; speedup vs baseline: 2.0585x; 2.0585x over previous
//
#include <hip/hip_runtime.h>
#include <hip/hip_bf16.h>
#include <stdint.h>

constexpr int BB = 4;
constexpr int SS = 2048;
constexpr int DD = 768;
constexpr int HH = 12;
constexpr int DKK = 64;
constexpr int DFF2 = 3072;
constexpr int MR = BB * SS;   // 8192 rows

typedef __attribute__((ext_vector_type(4))) short short4v;
typedef __attribute__((ext_vector_type(8))) short short8v;
typedef __attribute__((ext_vector_type(4))) float f32x4;
typedef __attribute__((ext_vector_type(4))) float float4v;

static __device__ inline short f2bs(float f) {
    __hip_bfloat16 h = __float2bfloat16(f);
    return (short)__builtin_bit_cast(unsigned short, h);
}
static __device__ inline float bs2f(short s) {
    __hip_bfloat16 h = __builtin_bit_cast(__hip_bfloat16, (unsigned short)s);
    return __bfloat162float(h);
}

static __device__ inline void glds16(const void* g, void* l) {
    __builtin_amdgcn_global_load_lds(
        (const __attribute__((address_space(1))) void*)g,
        (__attribute__((address_space(3))) void*)l, 16, 0, 0);
}

// ---------------- cast fp32 -> bf16 ----------------
__global__ __launch_bounds__(256) void cast_f32_bf16(const float* __restrict__ in,
                                                     short* __restrict__ out, int n) {
    int i = (blockIdx.x * 256 + threadIdx.x) * 4;
    if (i < n) {
        float4v v = *(const float4v*)&in[i];
        short4v o;
        o[0] = f2bs(v[0]); o[1] = f2bs(v[1]); o[2] = f2bs(v[2]); o[3] = f2bs(v[3]);
        *(short4v*)&out[i] = o;
    }
}

// ---------------- transpose + cast: Wt[n][k] = W[k][n] ----------------
__global__ __launch_bounds__(256) void transpose_cast(const float* __restrict__ W,
                                                      short* __restrict__ Wt, int K, int N) {
    __shared__ float tile[32][33];
    int n0 = blockIdx.x * 32, k0 = blockIdx.y * 32;
    int tx = threadIdx.x & 31, ty = threadIdx.x >> 5;
    #pragma unroll
    for (int i = 0; i < 32; i += 8)
        tile[ty + i][tx] = W[(size_t)(k0 + ty + i) * N + n0 + tx];
    __syncthreads();
    #pragma unroll
    for (int i = 0; i < 32; i += 8)
        Wt[(size_t)(n0 + ty + i) * K + k0 + tx] = f2bs(tile[tx][ty + i]);
}

// ---------------- V transpose: Vt[b,h,d,s] = V[b,h,s,d] ----------------
__global__ __launch_bounds__(256) void vtrans(const short* __restrict__ V,
                                              short* __restrict__ Vt) {
    __shared__ short t[64][72];
    const int tid = threadIdx.x;
    const size_t base = (size_t)blockIdx.y * SS * DKK;
    const int s0 = blockIdx.x * 64;
    int r = tid >> 3, c = (tid & 7) * 8;
    #pragma unroll
    for (int it = 0; it < 2; it++)
        *(short8v*)&t[it * 32 + r][c] =
            *(const short8v*)&V[base + (size_t)(s0 + it * 32 + r) * DKK + c];
    __syncthreads();
    int d = tid >> 2, sc0 = (tid & 3) * 16;
    #pragma unroll
    for (int half = 0; half < 2; half++) {
        short8v o;
        #pragma unroll
        for (int e = 0; e < 8; e++) o[e] = t[sc0 + half * 8 + e][d];
        *(short8v*)&Vt[base + (size_t)d * SS + s0 + sc0 + half * 8] = o;
    }
}

// ---------------- GEMM: C[M][N] = A[M][K] @ Bt[N][K]^T, bf16 MFMA (m97 structure) ----
// Fragments are read as CONTIGUOUS 16B (k-permuted identically for A and B: exact).
// EPI: 0 = +bias, store bf16 row-major
//      1 = +bias, relu, store bf16 row-major
//      2 = QKV scatter: +bias{q,k,v}, q *= 0.125*log2(e), all row-major [B,H,S,64]
template <int EPI>
__global__ __launch_bounds__(256) void gemm_bt(
    const short* __restrict__ A, const short* __restrict__ Bt,
    int Nn, int Kn,
    const float* __restrict__ bias0, const float* __restrict__ bias1,
    const float* __restrict__ bias2,
    short* __restrict__ out0, short* __restrict__ out1, short* __restrict__ out2) {
    __shared__ alignas(16) short sA[128 * 32];
    __shared__ alignas(16) short sB[128 * 32];
    const int tid = threadIdx.x;
    const int wave = tid >> 6, lane = tid & 63;
    const int g = lane >> 4, qq = lane & 15;
    const int wm = (wave >> 1) * 64, wn = (wave & 1) * 64;

    // XCD-aware block swizzle (all grids have nwg % 8 == 0)
    const int gx = gridDim.x;
    const int nwg = gx * gridDim.y;
    const int wgid = blockIdx.y * gx + blockIdx.x;
    const int cpx = nwg >> 3;
    const int swz = (wgid & 7) * cpx + (wgid >> 3);
    const int bx = swz % gx, by = swz / gx;
    const int m0 = by * 128, n0 = bx * 128;

    // staging: tile 128x32 shorts = 8192B; wave w deposits chunks [w*1024B) and [4096+w*1024B)
    const int e0 = wave * 512 + lane * 8;      // shorts
    const int r0 = e0 >> 5, c0 = e0 & 31;
    short* lA0 = &sA[wave * 512]; short* lA1 = &sA[wave * 512 + 2048];
    short* lB0 = &sB[wave * 512]; short* lB1 = &sB[wave * 512 + 2048];

    const f32x4 zero = {0.0f, 0.0f, 0.0f, 0.0f};
    f32x4 acc[4][4];
    #pragma unroll
    for (int i = 0; i < 4; i++)
        #pragma unroll
        for (int j = 0; j < 4; j++) acc[i][j] = zero;

    for (int k0 = 0; k0 < Kn; k0 += 32) {
        __syncthreads();
        glds16(&A[(size_t)(m0 + r0) * Kn + k0 + c0], lA0);
        glds16(&A[(size_t)(m0 + r0 + 64) * Kn + k0 + c0], lA1);
        glds16(&Bt[(size_t)(n0 + r0) * Kn + k0 + c0], lB0);
        glds16(&Bt[(size_t)(n0 + r0 + 64) * Kn + k0 + c0], lB1);
        __syncthreads();
        short8v af[4], bf[4];
        #pragma unroll
        for (int i = 0; i < 4; i++) {
            af[i] = *(const short8v*)&sA[(wm + i * 16 + qq) * 32 + 8 * g];
            bf[i] = *(const short8v*)&sB[(wn + i * 16 + qq) * 32 + 8 * g];
        }
        #pragma unroll
        for (int i = 0; i < 4; i++)
            #pragma unroll
            for (int j = 0; j < 4; j++)
                acc[i][j] = __builtin_amdgcn_mfma_f32_16x16x32_bf16(af[i], bf[j], acc[i][j], 0, 0, 0);
    }

    if (EPI == 2) {
        int which = bx / 6;   // 0=Q 1=K 2=V  (n0 = bx*128, DD = 768)
        const float* bias = (which == 0) ? bias0 : ((which == 1) ? bias1 : bias2);
        short* outp = (which == 0) ? out0 : ((which == 1) ? out1 : out2);
        float scale = (which == 0) ? 0.125f * 1.44269504088896f : 1.0f;
        #pragma unroll
        for (int i = 0; i < 4; i++)
            #pragma unroll
            for (int j = 0; j < 4; j++)
                #pragma unroll
                for (int r = 0; r < 4; r++) {
                    int row = m0 + wm + i * 16 + g * 4 + r;
                    int col = n0 - which * DD + wn + j * 16 + qq;
                    float vv = (acc[i][j][r] + bias[col]) * scale;
                    int b_ = row >> 11, s_ = row & 2047;
                    int h_ = col >> 6, d_ = col & 63;
                    outp[(((size_t)(b_ * HH + h_)) * SS + s_) * DKK + d_] = f2bs(vv);
                }
    } else {
        #pragma unroll
        for (int i = 0; i < 4; i++)
            #pragma unroll
            for (int j = 0; j < 4; j++)
                #pragma unroll
                for (int r = 0; r < 4; r++) {
                    int row = m0 + wm + i * 16 + g * 4 + r;
                    int col = n0 + wn + j * 16 + qq;
                    float vv = acc[i][j][r] + bias0[col];
                    if (EPI == 1) vv = fmaxf(vv, 0.0f);
                    out0[(size_t)row * Nn + col] = f2bs(vv);
                }
    }
}

// ---------------- flash attention, KVBLK=64, swizzled LDS, contiguous b128 frags ----
// Q pre-scaled by 0.125*log2(e): softmax computed in exp2 domain.
__global__ __launch_bounds__(256) void attn_kernel(
    const short* __restrict__ Q, const short* __restrict__ Kb,
    const short* __restrict__ Vt, const int* __restrict__ mask,
    short* __restrict__ ctx) {
    __shared__ alignas(16) short sK[64 * 64];
    __shared__ alignas(16) short sV[64 * 64];
    __shared__ alignas(16) short sP[4 * 16 * 64];
    const int tid = threadIdx.x;
    const int wave = tid >> 6, lane = tid & 63;
    const int g = lane >> 4, qq = lane & 15;
    const int bh = blockIdx.y;
    const int b_ = bh / HH, h_ = bh % HH;
    const int q0 = blockIdx.x * 64 + wave * 16;
    const size_t base = (size_t)bh * SS * DKK;
    char* kbase = (char*)sK;
    char* vbase = (char*)sV;
    char* pbase = (char*)sP + wave * 2048;

    // Q fragments: contiguous 16B per lane (d = c*32 + 8g .. +7)
    short8v aq[2];
    #pragma unroll
    for (int c = 0; c < 2; c++)
        aq[c] = *(const short8v*)&Q[base + (size_t)(q0 + qq) * DKK + c * 32 + 8 * g];

    const f32x4 zero = {0.0f, 0.0f, 0.0f, 0.0f};
    f32x4 cacc[4];
    #pragma unroll
    for (int i = 0; i < 4; i++) cacc[i] = zero;
    float mrow[4], lsum[4];
    #pragma unroll
    for (int r = 0; r < 4; r++) { mrow[r] = -INFINITY; lsum[r] = 0.0f; }

    const int sr = tid >> 3;            // 0..31 (staging row)
    const int scb = (tid & 7) * 16;     // byte chunk within 128B row
    const int rsz = (qq & 7) << 4;      // read-side swizzle for rows == qq (mod 8)

    for (int kv0 = 0; kv0 < SS; kv0 += 64) {
        __syncthreads();
        #pragma unroll
        for (int it = 0; it < 2; it++) {
            int r = it * 32 + sr;
            int sw = scb ^ ((r & 7) << 4);
            *(short8v*)(kbase + r * 128 + sw) =
                *(const short8v*)&Kb[base + (size_t)(kv0 + r) * DKK + scb / 2];
            *(short8v*)(vbase + r * 128 + sw) =
                *(const short8v*)&Vt[base + (size_t)r * SS + kv0 + scb / 2];
        }
        __syncthreads();

        // scores = Q @ K^T
        f32x4 sc[4];
        __builtin_amdgcn_s_setprio(1);
        #pragma unroll
        for (int nf = 0; nf < 4; nf++) {
            const char* kr = kbase + (nf * 16 + qq) * 128;
            f32x4 z = zero;
            z = __builtin_amdgcn_mfma_f32_16x16x32_bf16(
                aq[0], *(const short8v*)(kr + ((16 * g) ^ rsz)), z, 0, 0, 0);
            z = __builtin_amdgcn_mfma_f32_16x16x32_bf16(
                aq[1], *(const short8v*)(kr + ((64 + 16 * g) ^ rsz)), z, 0, 0, 0);
            sc[nf] = z;
        }
        __builtin_amdgcn_s_setprio(0);

        // mask (column-wise; scores already in log2 units)
        #pragma unroll
        for (int nf = 0; nf < 4; nf++) {
            if (mask[b_ * SS + kv0 + nf * 16 + qq] == 0) {
                #pragma unroll
                for (int r = 0; r < 4; r++) sc[nf][r] = -1.5e9f;
            }
        }

        // online softmax (row q = 4g+r lives on the 16 lanes sharing g)
        float tmax[4];
        #pragma unroll
        for (int r = 0; r < 4; r++) {
            float t = fmaxf(fmaxf(sc[0][r], sc[1][r]), fmaxf(sc[2][r], sc[3][r]));
            t = fmaxf(t, __shfl_xor(t, 1));
            t = fmaxf(t, __shfl_xor(t, 2));
            t = fmaxf(t, __shfl_xor(t, 4));
            t = fmaxf(t, __shfl_xor(t, 8));
            tmax[r] = t;
        }
        bool nomax = tmax[0] <= mrow[0] && tmax[1] <= mrow[1] &&
                     tmax[2] <= mrow[2] && tmax[3] <= mrow[3];
        if (!__all(nomax)) {
            #pragma unroll
            for (int r = 0; r < 4; r++) {
                float mnew = fmaxf(mrow[r], tmax[r]);
                float alpha = exp2f(mrow[r] - mnew);
                mrow[r] = mnew;
                lsum[r] *= alpha;
                #pragma unroll
                for (int nf = 0; nf < 4; nf++) cacc[nf][r] *= alpha;
            }
        }
        #pragma unroll
        for (int r = 0; r < 4; r++) {
            float ps = 0.0f;
            char* pr = pbase + (g * 4 + r) * 128;
            int rs2 = ((g * 4 + r) & 7) << 4;
            #pragma unroll
            for (int nf = 0; nf < 4; nf++) {
                float p = exp2f(sc[nf][r] - mrow[r]);
                ps += p;
                int cb = (nf * 16 + qq) * 2;
                *(short*)(pr + ((cb & 0x70) ^ rs2) + (cb & 15)) = f2bs(p);
            }
            lsum[r] += ps;
        }

        // PV: pa = P[q=qq][kv chunks], vf = V^T[d][kv chunks]
        short8v pa[2];
        const char* prd = pbase + qq * 128;
        #pragma unroll
        for (int c = 0; c < 2; c++)
            pa[c] = *(const short8v*)(prd + ((c * 64 + 16 * g) ^ rsz));
        __builtin_amdgcn_s_setprio(1);
        #pragma unroll
        for (int nf = 0; nf < 4; nf++) {
            const char* vr = vbase + (nf * 16 + qq) * 128;
            cacc[nf] = __builtin_amdgcn_mfma_f32_16x16x32_bf16(
                pa[0], *(const short8v*)(vr + ((16 * g) ^ rsz)), cacc[nf], 0, 0, 0);
            cacc[nf] = __builtin_amdgcn_mfma_f32_16x16x32_bf16(
                pa[1], *(const short8v*)(vr + ((64 + 16 * g) ^ rsz)), cacc[nf], 0, 0, 0);
        }
        __builtin_amdgcn_s_setprio(0);
    }

    // final l reduction (deferred out of the loop)
    #pragma unroll
    for (int r = 0; r < 4; r++) {
        float s = lsum[r];
        s += __shfl_xor(s, 1); s += __shfl_xor(s, 2);
        s += __shfl_xor(s, 4); s += __shfl_xor(s, 8);
        lsum[r] = 1.0f / s;
    }
    #pragma unroll
    for (int nf = 0; nf < 4; nf++)
        #pragma unroll
        for (int r = 0; r < 4; r++) {
            int row = q0 + g * 4 + r;
            int col = h_ * DKK + nf * 16 + qq;
            ctx[(size_t)(b_ * SS + row) * DD + col] = f2bs(cacc[nf][r] * lsum[r]);
        }
}

// ---------------- layernorm: out = LN(in1_f32 + in2_bf16) ----------------
template <int WB, int WF>
__global__ __launch_bounds__(256) void ln_fused(
    const float* __restrict__ in1, const short* __restrict__ in2,
    const float* __restrict__ gw, const float* __restrict__ bw,
    short* __restrict__ outb, float* __restrict__ outf) {
    const int row = blockIdx.x;
    const int tid = threadIdx.x;
    float v[3];
    #pragma unroll
    for (int i = 0; i < 3; i++) {
        int c = tid + i * 256;
        v[i] = in1[(size_t)row * DD + c] + bs2f(in2[(size_t)row * DD + c]);
    }
    float s = v[0] + v[1] + v[2];
    float s2 = v[0] * v[0] + v[1] * v[1] + v[2] * v[2];
    #pragma unroll
    for (int off = 1; off < 64; off <<= 1) {
        s += __shfl_xor(s, off);
        s2 += __shfl_xor(s2, off);
    }
    __shared__ float red[8];
    int wv = tid >> 6;
    if ((tid & 63) == 0) { red[wv] = s; red[4 + wv] = s2; }
    __syncthreads();
    s = red[0] + red[1] + red[2] + red[3];
    s2 = red[4] + red[5] + red[6] + red[7];
    float mu = s / DD;
    float var = s2 / DD - mu * mu;
    float rs = rsqrtf(var + 1e-5f);
    #pragma unroll
    for (int i = 0; i < 3; i++) {
        int c = tid + i * 256;
        float y = (v[i] - mu) * rs * gw[c] + bw[c];
        if (WB) outb[(size_t)row * DD + c] = f2bs(y);
        if (WF) outf[(size_t)row * DD + c] = y;
    }
}

extern "C" void kernel_launch(void* const* d_in, const int* in_sizes, int n_in,
                              void* d_out, int out_size, void* d_ws, size_t ws_size,
                              hipStream_t stream) {
    (void)in_sizes; (void)n_in; (void)out_size; (void)ws_size;
    const float* src = (const float*)d_in[0];
    const int* mask = (const int*)d_in[1];
    const float* Wq = (const float*)d_in[2];
    const float* bq = (const float*)d_in[3];
    const float* Wk = (const float*)d_in[4];
    const float* bk = (const float*)d_in[5];
    const float* Wv = (const float*)d_in[6];
    const float* bv = (const float*)d_in[7];
    const float* Wo = (const float*)d_in[8];
    const float* bo = (const float*)d_in[9];
    const float* W1 = (const float*)d_in[10];
    const float* b1 = (const float*)d_in[11];
    const float* W2 = (const float*)d_in[12];
    const float* b2 = (const float*)d_in[13];
    const float* ln1_g = (const float*)d_in[14];
    const float* ln1_b = (const float*)d_in[15];
    const float* ln2_g = (const float*)d_in[16];
    const float* ln2_b = (const float*)d_in[17];

    char* ws = (char*)d_ws;
    const size_t SB = (size_t)MR * DD * 2;            // 12582912 bytes
    short* src_b  = (short*)(ws);                     // R0: src_bf16 / attn_out / ffn2_out
    short* Wqkv_t = (short*)(ws + SB);                // R1
    short* qb     = (short*)(ws + SB + 3538944);      // R2: q,k,v,ctx (hb aliases all)
    short* kb_    = qb + (size_t)MR * DD;
    short* vb_    = kb_ + (size_t)MR * DD;            // V row-major
    short* ctxb   = vb_ + (size_t)MR * DD;
    short* hb     = qb;                               // [8192,3072] bf16
    short* Wo_t   = (short*)(ws + SB + 3538944 + 4 * SB);          // R3
    short* x_b    = (short*)(ws + SB + 3538944 + 4 * SB + 1179648);// R4 (Vt aliases, dead before LN1)
    short* W1_t   = (short*)((char*)x_b + SB);                     // R5
    short* W2_t   = (short*)((char*)W1_t + 4718592);               // R6
    float* x_f    = (float*)((char*)W2_t + 4718592);               // R7
    short* vt_    = x_b;                              // V^T [B,H,64,S], aliases x_b
    short* attn_b = src_b;
    short* ffn_b  = src_b;

    // 1. casts / transposes
    cast_f32_bf16<<<(MR * DD) / 1024, 256, 0, stream>>>(src, src_b, MR * DD);
    transpose_cast<<<dim3(24, 24), 256, 0, stream>>>(Wq, Wqkv_t, DD, DD);
    transpose_cast<<<dim3(24, 24), 256, 0, stream>>>(Wk, Wqkv_t + DD * DD, DD, DD);
    transpose_cast<<<dim3(24, 24), 256, 0, stream>>>(Wv, Wqkv_t + 2 * DD * DD, DD, DD);
    transpose_cast<<<dim3(24, 24), 256, 0, stream>>>(Wo, Wo_t, DD, DD);
    transpose_cast<<<dim3(96, 24), 256, 0, stream>>>(W1, W1_t, DD, DFF2);
    transpose_cast<<<dim3(24, 96), 256, 0, stream>>>(W2, W2_t, DFF2, DD);

    // 2. QKV projection (fused, N=2304), all outputs row-major [B,H,S,64]
    gemm_bt<2><<<dim3(2304 / 128, MR / 128), 256, 0, stream>>>(
        src_b, Wqkv_t, 2304, DD, bq, bk, bv, qb, kb_, vb_);

    // 2b. V transpose -> [B,H,64,S]
    vtrans<<<dim3(SS / 64, BB * HH), 256, 0, stream>>>(vb_, vt_);

    // 3. attention
    attn_kernel<<<dim3(SS / 64, BB * HH), 256, 0, stream>>>(qb, kb_, vt_, mask, ctxb);

    // 4. output projection
    gemm_bt<0><<<dim3(DD / 128, MR / 128), 256, 0, stream>>>(
        ctxb, Wo_t, DD, DD, bo, nullptr, nullptr, attn_b, nullptr, nullptr);

    // 5. LN1: x = LN(src + attn_out) -> bf16 + fp32
    ln_fused<1, 1><<<MR, 256, 0, stream>>>(src, attn_b, ln1_g, ln1_b, x_b, x_f);

    // 6. FFN
    gemm_bt<1><<<dim3(DFF2 / 128, MR / 128), 256, 0, stream>>>(
        x_b, W1_t, DFF2, DD, b1, nullptr, nullptr, hb, nullptr, nullptr);
    gemm_bt<0><<<dim3(DD / 128, MR / 128), 256, 0, stream>>>(
        hb, W2_t, DD, DFF2, b2, nullptr, nullptr, ffn_b, nullptr, nullptr);

    // 7. LN2 -> fp32 output
    ln_fused<0, 1><<<MR, 256, 0, stream>>>(x_f, ffn_b, ln2_g, ln2_b, nullptr, (float*)d_out);
}

// Round 4
// 376.392 us; speedup vs baseline: 2.2606x; 1.0982x over previous
//
#include <hip/hip_runtime.h>
#include <hip/hip_bf16.h>
#include <stdint.h>

constexpr int BB = 4;
constexpr int SS = 2048;
constexpr int DD = 768;
constexpr int HH = 12;
constexpr int DKK = 64;
constexpr int DFF2 = 3072;
constexpr int MR = BB * SS;   // 8192 rows

typedef __attribute__((ext_vector_type(4))) short short4v;
typedef __attribute__((ext_vector_type(8))) short short8v;
typedef __attribute__((ext_vector_type(4))) float f32x4;
typedef __attribute__((ext_vector_type(16))) float f32x16;
typedef __attribute__((ext_vector_type(4))) float float4v;
typedef __attribute__((ext_vector_type(4))) unsigned int u32x4;

static __device__ inline short f2bs(float f) {
    __hip_bfloat16 h = __float2bfloat16(f);
    return (short)__builtin_bit_cast(unsigned short, h);
}
static __device__ inline float bs2f(short s) {
    __hip_bfloat16 h = __builtin_bit_cast(__hip_bfloat16, (unsigned short)s);
    return __bfloat162float(h);
}

static __device__ inline void glds16(const void* g, void* l) {
    __builtin_amdgcn_global_load_lds(
        (const __attribute__((address_space(1))) void*)g,
        (__attribute__((address_space(3))) void*)l, 16, 0, 0);
}

static __device__ inline unsigned cvtpk(float a, float b) {
    unsigned d;
    asm("v_cvt_pk_bf16_f32 %0, %1, %2" : "=v"(d) : "v"(a), "v"(b));
    return d;
}
static __device__ inline short8v pk4(unsigned a, unsigned b, unsigned c, unsigned d) {
    u32x4 w; w[0] = a; w[1] = b; w[2] = c; w[3] = d;
    return __builtin_bit_cast(short8v, w);
}
static __device__ inline short8v ldsv(const char* p, int off) {
    short4v a = *(const short4v*)(p + off);
    short4v b = *(const short4v*)(p + (off ^ 16));
    return __builtin_shufflevector(a, b, 0, 1, 2, 3, 4, 5, 6, 7);
}

// ---------------- cast fp32 -> bf16 ----------------
__global__ __launch_bounds__(256) void cast_f32_bf16(const float* __restrict__ in,
                                                     short* __restrict__ out, int n) {
    int i = (blockIdx.x * 256 + threadIdx.x) * 4;
    if (i < n) {
        float4v v = *(const float4v*)&in[i];
        short4v o;
        o[0] = f2bs(v[0]); o[1] = f2bs(v[1]); o[2] = f2bs(v[2]); o[3] = f2bs(v[3]);
        *(short4v*)&out[i] = o;
    }
}

// ---------------- transpose + cast: Wt[n][k] = W[k][n] ----------------
__global__ __launch_bounds__(256) void transpose_cast(const float* __restrict__ W,
                                                      short* __restrict__ Wt, int K, int N) {
    __shared__ float tile[32][33];
    int n0 = blockIdx.x * 32, k0 = blockIdx.y * 32;
    int tx = threadIdx.x & 31, ty = threadIdx.x >> 5;
    #pragma unroll
    for (int i = 0; i < 32; i += 8)
        tile[ty + i][tx] = W[(size_t)(k0 + ty + i) * N + n0 + tx];
    __syncthreads();
    #pragma unroll
    for (int i = 0; i < 32; i += 8)
        Wt[(size_t)(n0 + ty + i) * K + k0 + tx] = f2bs(tile[tx][ty + i]);
}

// ---------------- V transpose: Vt[b,h,d,s] = V[b,h,s,d] ----------------
__global__ __launch_bounds__(256) void vtrans(const short* __restrict__ V,
                                              short* __restrict__ Vt) {
    __shared__ short t[64][72];
    const int tid = threadIdx.x;
    const size_t base = (size_t)blockIdx.y * SS * DKK;
    const int s0 = blockIdx.x * 64;
    int r = tid >> 3, c = (tid & 7) * 8;
    #pragma unroll
    for (int it = 0; it < 2; it++)
        *(short8v*)&t[it * 32 + r][c] =
            *(const short8v*)&V[base + (size_t)(s0 + it * 32 + r) * DKK + c];
    __syncthreads();
    int d = tid >> 2, sc0 = (tid & 3) * 16;
    #pragma unroll
    for (int half = 0; half < 2; half++) {
        short8v o;
        #pragma unroll
        for (int e = 0; e < 8; e++) o[e] = t[sc0 + half * 8 + e][d];
        *(short8v*)&Vt[base + (size_t)d * SS + s0 + sc0 + half * 8] = o;
    }
}

// ---------------- GEMM: C[M][N] = A[M][K] @ Bt[N][K]^T, bf16 MFMA (m97 structure) ----
template <int EPI>
__global__ __launch_bounds__(256) void gemm_bt(
    const short* __restrict__ A, const short* __restrict__ Bt,
    int Nn, int Kn,
    const float* __restrict__ bias0, const float* __restrict__ bias1,
    const float* __restrict__ bias2,
    short* __restrict__ out0, short* __restrict__ out1, short* __restrict__ out2) {
    __shared__ alignas(16) short sA[128 * 32];
    __shared__ alignas(16) short sB[128 * 32];
    const int tid = threadIdx.x;
    const int wave = tid >> 6, lane = tid & 63;
    const int g = lane >> 4, qq = lane & 15;
    const int wm = (wave >> 1) * 64, wn = (wave & 1) * 64;

    const int gx = gridDim.x;
    const int nwg = gx * gridDim.y;
    const int wgid = blockIdx.y * gx + blockIdx.x;
    const int cpx = nwg >> 3;
    const int swz = (wgid & 7) * cpx + (wgid >> 3);
    const int bx = swz % gx, by = swz / gx;
    const int m0 = by * 128, n0 = bx * 128;

    const int e0 = wave * 512 + lane * 8;
    const int r0 = e0 >> 5, c0 = e0 & 31;
    short* lA0 = &sA[wave * 512]; short* lA1 = &sA[wave * 512 + 2048];
    short* lB0 = &sB[wave * 512]; short* lB1 = &sB[wave * 512 + 2048];

    const f32x4 zero = {0.0f, 0.0f, 0.0f, 0.0f};
    f32x4 acc[4][4];
    #pragma unroll
    for (int i = 0; i < 4; i++)
        #pragma unroll
        for (int j = 0; j < 4; j++) acc[i][j] = zero;

    for (int k0 = 0; k0 < Kn; k0 += 32) {
        __syncthreads();
        glds16(&A[(size_t)(m0 + r0) * Kn + k0 + c0], lA0);
        glds16(&A[(size_t)(m0 + r0 + 64) * Kn + k0 + c0], lA1);
        glds16(&Bt[(size_t)(n0 + r0) * Kn + k0 + c0], lB0);
        glds16(&Bt[(size_t)(n0 + r0 + 64) * Kn + k0 + c0], lB1);
        __syncthreads();
        short8v af[4], bf[4];
        #pragma unroll
        for (int i = 0; i < 4; i++) {
            af[i] = *(const short8v*)&sA[(wm + i * 16 + qq) * 32 + 8 * g];
            bf[i] = *(const short8v*)&sB[(wn + i * 16 + qq) * 32 + 8 * g];
        }
        #pragma unroll
        for (int i = 0; i < 4; i++)
            #pragma unroll
            for (int j = 0; j < 4; j++)
                acc[i][j] = __builtin_amdgcn_mfma_f32_16x16x32_bf16(af[i], bf[j], acc[i][j], 0, 0, 0);
    }

    if (EPI == 2) {
        int which = bx / 6;
        const float* bias = (which == 0) ? bias0 : ((which == 1) ? bias1 : bias2);
        short* outp = (which == 0) ? out0 : ((which == 1) ? out1 : out2);
        float scale = (which == 0) ? 0.125f * 1.44269504088896f : 1.0f;
        #pragma unroll
        for (int i = 0; i < 4; i++)
            #pragma unroll
            for (int j = 0; j < 4; j++)
                #pragma unroll
                for (int r = 0; r < 4; r++) {
                    int row = m0 + wm + i * 16 + g * 4 + r;
                    int col = n0 - which * DD + wn + j * 16 + qq;
                    float vv = (acc[i][j][r] + bias[col]) * scale;
                    int b_ = row >> 11, s_ = row & 2047;
                    int h_ = col >> 6, d_ = col & 63;
                    outp[(((size_t)(b_ * HH + h_)) * SS + s_) * DKK + d_] = f2bs(vv);
                }
    } else {
        #pragma unroll
        for (int i = 0; i < 4; i++)
            #pragma unroll
            for (int j = 0; j < 4; j++)
                #pragma unroll
                for (int r = 0; r < 4; r++) {
                    int row = m0 + wm + i * 16 + g * 4 + r;
                    int col = n0 + wn + j * 16 + qq;
                    float vv = acc[i][j][r] + bias0[col];
                    if (EPI == 1) vv = fmaxf(vv, 0.0f);
                    out0[(size_t)row * Nn + col] = f2bs(vv);
                }
    }
}

// ---------------- flash attention: swapped QK^T, 32x32 MFMA, in-register softmax ----
// block = 256 thr (4 warps x 32 q-rows = 128 q/block). KVBLK = 64.
// Q pre-scaled by 0.125*log2(e).
__global__ __launch_bounds__(256) void attn_kernel(
    const short* __restrict__ Q, const short* __restrict__ Kb,
    const short* __restrict__ Vt, const int* __restrict__ mask,
    short* __restrict__ ctx) {
    __shared__ alignas(16) short sK[64 * 64];   // [kv][d], XOR-swizzled rows
    __shared__ alignas(16) short sV[64 * 64];   // [d][kv], XOR-swizzled rows
    __shared__ float sAl[4][32];
    const int tid = threadIdx.x;
    const int wave = tid >> 6, lane = tid & 63;
    const int hi = lane >> 5, ln = lane & 31;

    // XCD swizzle: 768 wgs -> 96 consecutive (6 bh x 16 qb) per XCD
    int flat = blockIdx.y * gridDim.x + blockIdx.x;   // y = bh (48), x = qb (16)
    int nw = (flat & 7) * 96 + (flat >> 3);
    const int bh = nw >> 4, qb = nw & 15;
    const int b_ = bh / HH, h_ = bh % HH;
    const int q0 = qb * 128 + wave * 32;
    const size_t base = (size_t)bh * SS * DKK;

    // Q fragments (B operand): lane holds Q[q0+ln][d slots], 4 chunks of K=16
    short8v qf[4];
    {
        const short* qp = &Q[base + (size_t)(q0 + ln) * DKK];
        #pragma unroll
        for (int c = 0; c < 4; c++) {
            short4v a0 = *(const short4v*)(qp + 16 * c + 4 * hi);
            short4v a1 = *(const short4v*)(qp + 16 * c + 8 + 4 * hi);
            qf[c] = __builtin_shufflevector(a0, a1, 0, 1, 2, 3, 4, 5, 6, 7);
        }
    }

    f32x16 O0, O1;
    #pragma unroll
    for (int r = 0; r < 16; r++) { O0[r] = 0.0f; O1[r] = 0.0f; }
    float mreg = -INFINITY, lreg = 0.0f;

    // staging: linear LDS dest (wave w: base + 1024w + 16*lane), pre-swizzled source col
    const int rowA = 8 * wave + (lane >> 3);
    const int cbl = ((lane & 7) * 16) ^ ((lane >> 3) << 4);   // logical byte col
    short* kdst0 = sK + 512 * wave;  short* kdst1 = sK + 2048 + 512 * wave;
    short* vdst0 = sV + 512 * wave;  short* vdst1 = sV + 2048 + 512 * wave;

    const int rsz = (ln & 7) << 4;
    const char* kr0 = (const char*)sK + ln * 128;
    const char* kr1 = (const char*)sK + (32 + ln) * 128;
    const char* vr0 = (const char*)sV + ln * 128;
    const char* vr1 = (const char*)sV + (32 + ln) * 128;

    for (int kv0 = 0; kv0 < SS; kv0 += 64) {
        __syncthreads();
        glds16(&Kb[base + (size_t)(kv0 + rowA) * DKK + (cbl >> 1)], kdst0);
        glds16(&Kb[base + (size_t)(kv0 + rowA + 32) * DKK + (cbl >> 1)], kdst1);
        glds16(&Vt[base + (size_t)rowA * SS + kv0 + (cbl >> 1)], vdst0);
        glds16(&Vt[base + (size_t)(rowA + 32) * SS + kv0 + (cbl >> 1)], vdst1);
        __syncthreads();

        int mv = mask[b_ * SS + kv0 + lane];
        bool allm = __all(mv != 0);

        // S-tiles: lane owns q-col = ln; regs = kv rows (r&3)+8*(r>>2)+4*hi
        f32x16 s0, s1;
        #pragma unroll
        for (int r = 0; r < 16; r++) { s0[r] = 0.0f; s1[r] = 0.0f; }
        __builtin_amdgcn_s_setprio(1);
        #pragma unroll
        for (int c = 0; c < 4; c++) {
            int off = (32 * c + 8 * hi) ^ rsz;
            s0 = __builtin_amdgcn_mfma_f32_32x32x16_bf16(ldsv(kr0, off), qf[c], s0, 0, 0, 0);
            s1 = __builtin_amdgcn_mfma_f32_32x32x16_bf16(ldsv(kr1, off), qf[c], s1, 0, 0, 0);
        }
        __builtin_amdgcn_s_setprio(0);

        if (!allm) {
            #pragma unroll
            for (int r = 0; r < 16; r++) {
                int kvr = (r & 3) + 8 * (r >> 2) + 4 * hi;
                if (mask[b_ * SS + kv0 + kvr] == 0) s0[r] = -1.5e9f;
                if (mask[b_ * SS + kv0 + 32 + kvr] == 0) s1[r] = -1.5e9f;
            }
        }

        // in-lane row max over 32 scores + cross-half combine
        float pm = fmaxf(s0[0], s1[0]);
        #pragma unroll
        for (int r = 1; r < 16; r++) pm = fmaxf(pm, fmaxf(s0[r], s1[r]));
        pm = fmaxf(pm, __shfl_xor(pm, 32));

        // defer-max (THR=8): rescale only when some row grows past threshold
        if (!__all(pm - mreg <= 8.0f)) {
            float mnew = fmaxf(mreg, pm);
            float alpha = __builtin_amdgcn_exp2f(mreg - mnew);
            mreg = mnew;
            lreg *= alpha;
            sAl[wave][ln] = alpha;
            #pragma unroll
            for (int r = 0; r < 16; r++) {
                float av = sAl[wave][(r & 3) + 8 * (r >> 2) + 4 * hi];
                O0[r] *= av; O1[r] *= av;
            }
        }

        // exp2 + in-lane partial sum
        float ps = 0.0f;
        #pragma unroll
        for (int r = 0; r < 16; r++) {
            s0[r] = __builtin_amdgcn_exp2f(s0[r] - mreg); ps += s0[r];
            s1[r] = __builtin_amdgcn_exp2f(s1[r] - mreg); ps += s1[r];
        }
        lreg += ps;

        // pack P (C/D reg map == A-frag slot map): chunk = 8 consecutive regs
        short8v p00 = pk4(cvtpk(s0[0], s0[1]), cvtpk(s0[2], s0[3]),
                          cvtpk(s0[4], s0[5]), cvtpk(s0[6], s0[7]));
        short8v p01 = pk4(cvtpk(s0[8], s0[9]), cvtpk(s0[10], s0[11]),
                          cvtpk(s0[12], s0[13]), cvtpk(s0[14], s0[15]));
        short8v p10 = pk4(cvtpk(s1[0], s1[1]), cvtpk(s1[2], s1[3]),
                          cvtpk(s1[4], s1[5]), cvtpk(s1[6], s1[7]));
        short8v p11 = pk4(cvtpk(s1[8], s1[9]), cvtpk(s1[10], s1[11]),
                          cvtpk(s1[12], s1[13]), cvtpk(s1[14], s1[15]));

        // PV: O[q][d], A = P (rows q), B = V^T rows d; kv chunks of 16
        __builtin_amdgcn_s_setprio(1);
        #pragma unroll
        for (int cc = 0; cc < 4; cc++) {
            int off = (32 * cc + 8 * hi) ^ rsz;
            short8v pa = (cc == 0) ? p00 : (cc == 1) ? p01 : (cc == 2) ? p10 : p11;
            O0 = __builtin_amdgcn_mfma_f32_32x32x16_bf16(pa, ldsv(vr0, off), O0, 0, 0, 0);
            O1 = __builtin_amdgcn_mfma_f32_32x32x16_bf16(pa, ldsv(vr1, off), O1, 0, 0, 0);
        }
        __builtin_amdgcn_s_setprio(0);
    }

    // final: combine l across halves, divide, store
    lreg += __shfl_xor(lreg, 32);
    sAl[wave][ln] = 1.0f / lreg;
    #pragma unroll
    for (int r = 0; r < 16; r++) {
        int rho = (r & 3) + 8 * (r >> 2) + 4 * hi;
        float li = sAl[wave][rho];
        size_t rowoff = (size_t)(b_ * SS + q0 + rho) * DD + h_ * DKK;
        ctx[rowoff + ln] = f2bs(O0[r] * li);
        ctx[rowoff + 32 + ln] = f2bs(O1[r] * li);
    }
}

// ---------------- layernorm: out = LN(in1_f32 + in2_bf16) ----------------
template <int WB, int WF>
__global__ __launch_bounds__(256) void ln_fused(
    const float* __restrict__ in1, const short* __restrict__ in2,
    const float* __restrict__ gw, const float* __restrict__ bw,
    short* __restrict__ outb, float* __restrict__ outf) {
    const int row = blockIdx.x;
    const int tid = threadIdx.x;
    float v[3];
    #pragma unroll
    for (int i = 0; i < 3; i++) {
        int c = tid + i * 256;
        v[i] = in1[(size_t)row * DD + c] + bs2f(in2[(size_t)row * DD + c]);
    }
    float s = v[0] + v[1] + v[2];
    float s2 = v[0] * v[0] + v[1] * v[1] + v[2] * v[2];
    #pragma unroll
    for (int off = 1; off < 64; off <<= 1) {
        s += __shfl_xor(s, off);
        s2 += __shfl_xor(s2, off);
    }
    __shared__ float red[8];
    int wv = tid >> 6;
    if ((tid & 63) == 0) { red[wv] = s; red[4 + wv] = s2; }
    __syncthreads();
    s = red[0] + red[1] + red[2] + red[3];
    s2 = red[4] + red[5] + red[6] + red[7];
    float mu = s / DD;
    float var = s2 / DD - mu * mu;
    float rs = rsqrtf(var + 1e-5f);
    #pragma unroll
    for (int i = 0; i < 3; i++) {
        int c = tid + i * 256;
        float y = (v[i] - mu) * rs * gw[c] + bw[c];
        if (WB) outb[(size_t)row * DD + c] = f2bs(y);
        if (WF) outf[(size_t)row * DD + c] = y;
    }
}

extern "C" void kernel_launch(void* const* d_in, const int* in_sizes, int n_in,
                              void* d_out, int out_size, void* d_ws, size_t ws_size,
                              hipStream_t stream) {
    (void)in_sizes; (void)n_in; (void)out_size; (void)ws_size;
    const float* src = (const float*)d_in[0];
    const int* mask = (const int*)d_in[1];
    const float* Wq = (const float*)d_in[2];
    const float* bq = (const float*)d_in[3];
    const float* Wk = (const float*)d_in[4];
    const float* bk = (const float*)d_in[5];
    const float* Wv = (const float*)d_in[6];
    const float* bv = (const float*)d_in[7];
    const float* Wo = (const float*)d_in[8];
    const float* bo = (const float*)d_in[9];
    const float* W1 = (const float*)d_in[10];
    const float* b1 = (const float*)d_in[11];
    const float* W2 = (const float*)d_in[12];
    const float* b2 = (const float*)d_in[13];
    const float* ln1_g = (const float*)d_in[14];
    const float* ln1_b = (const float*)d_in[15];
    const float* ln2_g = (const float*)d_in[16];
    const float* ln2_b = (const float*)d_in[17];

    char* ws = (char*)d_ws;
    const size_t SB = (size_t)MR * DD * 2;            // 12582912 bytes
    short* src_b  = (short*)(ws);                     // R0: src_bf16 / attn_out / ffn2_out
    short* Wqkv_t = (short*)(ws + SB);                // R1
    short* qb     = (short*)(ws + SB + 3538944);      // R2: q,k,v,ctx (hb aliases all)
    short* kb_    = qb + (size_t)MR * DD;
    short* vb_    = kb_ + (size_t)MR * DD;            // V row-major
    short* ctxb   = vb_ + (size_t)MR * DD;
    short* hb     = qb;                               // [8192,3072] bf16
    short* Wo_t   = (short*)(ws + SB + 3538944 + 4 * SB);          // R3
    short* x_b    = (short*)(ws + SB + 3538944 + 4 * SB + 1179648);// R4
    short* W1_t   = (short*)((char*)x_b + SB);                     // R5
    short* W2_t   = (short*)((char*)W1_t + 4718592);               // R6
    float* x_f    = (float*)((char*)W2_t + 4718592);               // R7
    short* vt_    = x_b;                              // V^T [B,H,64,S], aliases x_b
    short* attn_b = src_b;
    short* ffn_b  = src_b;

    // 1. casts / transposes
    cast_f32_bf16<<<(MR * DD) / 1024, 256, 0, stream>>>(src, src_b, MR * DD);
    transpose_cast<<<dim3(24, 24), 256, 0, stream>>>(Wq, Wqkv_t, DD, DD);
    transpose_cast<<<dim3(24, 24), 256, 0, stream>>>(Wk, Wqkv_t + DD * DD, DD, DD);
    transpose_cast<<<dim3(24, 24), 256, 0, stream>>>(Wv, Wqkv_t + 2 * DD * DD, DD, DD);
    transpose_cast<<<dim3(24, 24), 256, 0, stream>>>(Wo, Wo_t, DD, DD);
    transpose_cast<<<dim3(96, 24), 256, 0, stream>>>(W1, W1_t, DD, DFF2);
    transpose_cast<<<dim3(24, 96), 256, 0, stream>>>(W2, W2_t, DFF2, DD);

    // 2. QKV projection (fused, N=2304), outputs row-major [B,H,S,64]
    gemm_bt<2><<<dim3(2304 / 128, MR / 128), 256, 0, stream>>>(
        src_b, Wqkv_t, 2304, DD, bq, bk, bv, qb, kb_, vb_);

    // 2b. V transpose -> [B,H,64,S]
    vtrans<<<dim3(SS / 64, BB * HH), 256, 0, stream>>>(vb_, vt_);

    // 3. attention (swapped-QK 32x32 structure)
    attn_kernel<<<dim3(SS / 128, BB * HH), 256, 0, stream>>>(qb, kb_, vt_, mask, ctxb);

    // 4. output projection
    gemm_bt<0><<<dim3(DD / 128, MR / 128), 256, 0, stream>>>(
        ctxb, Wo_t, DD, DD, bo, nullptr, nullptr, attn_b, nullptr, nullptr);

    // 5. LN1: x = LN(src + attn_out) -> bf16 + fp32
    ln_fused<1, 1><<<MR, 256, 0, stream>>>(src, attn_b, ln1_g, ln1_b, x_b, x_f);

    // 6. FFN
    gemm_bt<1><<<dim3(DFF2 / 128, MR / 128), 256, 0, stream>>>(
        x_b, W1_t, DFF2, DD, b1, nullptr, nullptr, hb, nullptr, nullptr);
    gemm_bt<0><<<dim3(DD / 128, MR / 128), 256, 0, stream>>>(
        hb, W2_t, DD, DFF2, b2, nullptr, nullptr, ffn_b, nullptr, nullptr);

    // 7. LN2 -> fp32 output
    ln_fused<0, 1><<<MR, 256, 0, stream>>>(x_f, ffn_b, ln2_g, ln2_b, nullptr, (float*)d_out);
}